// Round 1
// baseline (336.162 us; speedup 1.0000x reference)
//
#include <hip/hip_runtime.h>

#define H 512
#define NNODES 10000
#define NEDGES 160000
#define NLAYERS 5

typedef __attribute__((ext_vector_type(8))) short short8;
typedef __attribute__((ext_vector_type(4))) float floatx4;
typedef __attribute__((ext_vector_type(2))) float floatx2;

// ---------- helpers ----------
__device__ inline unsigned short f2bf(float v) {
    union { float f; unsigned int u; } x; x.f = v;
    unsigned int r = (x.u + 0x7fffu + ((x.u >> 16) & 1u)) >> 16;
    return (unsigned short)r;
}
__device__ inline float bf2f(unsigned short u) {
    union { unsigned int u; float f; } x; x.u = ((unsigned int)u) << 16; return x.f;
}
__device__ inline void gl_lds16(const void* g, void* l) {
    __builtin_amdgcn_global_load_lds((const __attribute__((address_space(1))) void*)g,
                                     (__attribute__((address_space(3))) void*)l, 16, 0, 0);
}

// ---------- prep kernels ----------
__global__ void zero_int(int* __restrict__ p, int n) {
    int i = blockIdx.x * blockDim.x + threadIdx.x;
    if (i < n) p[i] = 0;
}

__global__ void cvt_f32_bf16(const float* __restrict__ in, unsigned short* __restrict__ out, int n4) {
    int i = blockIdx.x * blockDim.x + threadIdx.x;
    if (i < n4) {
        float4 v = ((const float4*)in)[i];
        ushort4 o;
        o.x = f2bf(v.x); o.y = f2bf(v.y); o.z = f2bf(v.z); o.w = f2bf(v.w);
        ((ushort4*)out)[i] = o;
    }
}

// batched: z in [0,6): 5 layer weights + vw1. out[n][k] = in[k][n], bf16
__global__ void transpose_cvt6(const float* __restrict__ Wg, const float* __restrict__ vw1,
                               unsigned short* __restrict__ Wt) {
    __shared__ float tile[32][33];
    const int z = blockIdx.z;
    const float* in = (z < NLAYERS) ? (Wg + (size_t)z * H * H) : vw1;
    unsigned short* out = Wt + (size_t)z * H * H;
    const int bx = blockIdx.x * 32;
    const int by = blockIdx.y * 32;
    const int tx = threadIdx.x, ty = threadIdx.y;  // (32,8)
    for (int i = ty; i < 32; i += 8)
        tile[i][tx] = in[(size_t)(by + i) * H + bx + tx];
    __syncthreads();
    for (int i = ty; i < 32; i += 8)
        out[(size_t)(bx + i) * H + by + tx] = f2bf(tile[tx][i]);
}

__global__ void edge_hist(const int* __restrict__ rows, int* __restrict__ counts, int n) {
    int i = blockIdx.x * blockDim.x + threadIdx.x;
    if (i < n) atomicAdd(&counts[rows[i]], 1);
}

// prefix-sum of row counts PADDED to multiples of 8 (dummy edges have val=0
// -> exact no-ops in the accumulation; enables branch-free SpMM rounds)
__global__ __launch_bounds__(1024)
void scan_rows_pad(const int* __restrict__ counts, int* __restrict__ row_ptr, int n) {
    __shared__ int sums[1024];
    const int t = threadIdx.x;
    const int base = t * 16;
    int local[16];
    int s = 0;
#pragma unroll
    for (int i = 0; i < 16; ++i) {
        int idx = base + i;
        int v = (idx < n) ? ((counts[idx] + 7) & ~7) : 0;
        local[i] = s;
        s += v;
    }
    sums[t] = s;
    __syncthreads();
    for (int off = 1; off < 1024; off <<= 1) {
        int v = (t >= off) ? sums[t - off] : 0;
        __syncthreads();
        sums[t] += v;
        __syncthreads();
    }
    const int prefix = (t == 0) ? 0 : sums[t - 1];
#pragma unroll
    for (int i = 0; i < 16; ++i) {
        int idx = base + i;
        if (idx < n) row_ptr[idx] = prefix + local[i];
    }
    if (t == 0) row_ptr[n] = sums[1023];
}

__global__ void edge_scatter(const int* __restrict__ rows, const int* __restrict__ colsin,
                             const float* __restrict__ valsin, const int* __restrict__ row_ptr,
                             int* __restrict__ fill, int* __restrict__ colsout,
                             float* __restrict__ valsout, int n) {
    int i = blockIdx.x * blockDim.x + threadIdx.x;
    if (i < n) {
        int r = rows[i];
        int pos = row_ptr[r] + atomicAdd(&fill[r], 1);
        colsout[pos] = colsin[i];
        valsout[pos] = valsin[i];
    }
}

// ---------- GEMM body (128x64, BK=64, XOR k-slot swizzle, DOUBLE-BUFFERED) ----------
// Change vs r3: two LDS buffers; stage K-tile it+1 BEFORE computing tile it.
// The implicit vmcnt(0) at the single end-of-iter __syncthreads now lands
// AFTER ~200cy of ds_read+MFMA instead of immediately after issue -> the
// global->LDS latency is overlapped instead of serialized (grid is only
// 2.5 blocks/CU so cross-block overlap can't hide it). K order unchanged
// -> numerics bit-identical to r3.
__device__ __forceinline__ void gemm_tile_body(
    const unsigned short* __restrict__ A, const unsigned short* __restrict__ Bt,
    unsigned short* __restrict__ C, const float* __restrict__ bias,
    int has_bias_relu, int M, int tileM, int tileN,
    unsigned short* lsA, unsigned short* lsB) {
    const int t = threadIdx.x;
    const int lane = t & 63;
    const int wave = t >> 6;
    const int wm = wave >> 1, wn = wave & 1;
    const int quad = lane >> 4, r16 = lane & 15;

    floatx4 acc[4][2] = {};

    const unsigned short* ap[4];
#pragma unroll
    for (int q = 0; q < 4; ++q) {
        const int c = t + 256 * q;
        const int row = c >> 3;
        int g = tileM + row; if (g >= M) g = M - 1;
        ap[q] = A + (size_t)g * 512 + (((c & 7) ^ (row & 7)) * 8);
    }
    const unsigned short* bp[2];
#pragma unroll
    for (int q = 0; q < 2; ++q) {
        const int c = t + 256 * q;
        const int row = c >> 3;
        bp[q] = Bt + (size_t)(tileN + row) * 512 + (((c & 7) ^ (row & 7)) * 8);
    }

#define STAGE(buf, k0)                                                   \
    do {                                                                 \
        unsigned short* dA = lsA + (buf) * (128 * 64);                   \
        unsigned short* dB = lsB + (buf) * (64 * 64);                    \
        gl_lds16(ap[0] + (k0), dA + (size_t)t * 8);                      \
        gl_lds16(ap[1] + (k0), dA + (size_t)(t + 256) * 8);              \
        gl_lds16(ap[2] + (k0), dA + (size_t)(t + 512) * 8);              \
        gl_lds16(ap[3] + (k0), dA + (size_t)(t + 768) * 8);              \
        gl_lds16(bp[0] + (k0), dB + (size_t)t * 8);                      \
        gl_lds16(bp[1] + (k0), dB + (size_t)(t + 256) * 8);              \
    } while (0)

    STAGE(0, 0);
    __syncthreads();

#pragma unroll
    for (int it = 0; it < 8; ++it) {
        if (it < 7) STAGE((it + 1) & 1, (it + 1) * 64);  // prefetch next tile
        const unsigned short* cA = lsA + (it & 1) * (128 * 64);
        const unsigned short* cB = lsB + (it & 1) * (64 * 64);

        short8 af[4][2], bfr[2][2];
#pragma unroll
        for (int i = 0; i < 4; ++i) {
            const int row = wm * 64 + i * 16 + r16;
#pragma unroll
            for (int kk = 0; kk < 2; ++kk) {
                const int kcw = kk * 4 + quad;
                af[i][kk] = *(const short8*)&cA[(size_t)(row * 8 + (kcw ^ (row & 7))) * 8];
            }
        }
#pragma unroll
        for (int j = 0; j < 2; ++j) {
            const int row = wn * 32 + j * 16 + r16;
#pragma unroll
            for (int kk = 0; kk < 2; ++kk) {
                const int kcw = kk * 4 + quad;
                bfr[j][kk] = *(const short8*)&cB[(size_t)(row * 8 + (kcw ^ (row & 7))) * 8];
            }
        }
#pragma unroll
        for (int kk = 0; kk < 2; ++kk)  // K ascending -> numerics match r3 exactly
#pragma unroll
            for (int i = 0; i < 4; ++i)
#pragma unroll
                for (int j = 0; j < 2; ++j)
                    acc[i][j] = __builtin_amdgcn_mfma_f32_16x16x32_bf16(af[i][kk], bfr[j][kk], acc[i][j], 0, 0, 0);
        __syncthreads();  // one barrier per iter: drains my ds_reads + everyone's prefetch
    }
#undef STAGE

#pragma unroll
    for (int i = 0; i < 4; ++i) {
#pragma unroll
        for (int j = 0; j < 2; ++j) {
            const int col = tileN + wn * 32 + j * 16 + r16;
#pragma unroll
            for (int reg = 0; reg < 4; ++reg) {
                const int row = tileM + wm * 64 + i * 16 + quad * 4 + reg;
                if (row < M) {
                    float v = acc[i][j][reg];
                    if (has_bias_relu) { v += bias[col]; v = fmaxf(v, 0.f); }
                    C[(size_t)row * 512 + col] = f2bf(v);
                }
            }
        }
    }
}

// XCD-aware launch wrapper: grid = 640 linear blocks. Decode so that all 8
// N-slices of one M-tile share (L % 8) -> same XCD (round-robin dispatch
// heuristic) -> A-tile lands in that XCD's L2 once, reused 8x.
__global__ __launch_bounds__(256)
void gemm_bf16_xcd(const unsigned short* __restrict__ A, const unsigned short* __restrict__ Bt,
                   unsigned short* __restrict__ C, const float* __restrict__ bias,
                   int has_bias_relu, int M) {
    __shared__ __align__(16) unsigned short lsA[2 * 128 * 64];  // 32 KB (double-buffered)
    __shared__ __align__(16) unsigned short lsB[2 * 64 * 64];   // 16 KB
    const int L = blockIdx.x;
    const int m_low = L & 7;
    const int rest = L >> 3;         // 0..79
    const int n = rest & 7;          // 0..7
    const int m_high = rest >> 3;    // 0..9
    const int m = m_high * 8 + m_low;  // 0..79
    gemm_tile_body(A, Bt, C, bias, has_bias_relu, M, m * 128, n * 64, lsA, lsB);
}

// ---------- SpMM + bias + relu on padded CSR ----------
// Changes vs r3: (a) cols/vals for iteration i+8 prefetched during iteration i
// (removes the col-load -> gather serial dependency at the top of each iter);
// (b) bf16 unpack done on packed dwords (<<16 / &0xffff0000) with float2
// accumulators -> half the unpack VALU ops, packed-FMA friendly.
// Accumulation order (u outer, j inner, fma) is IDENTICAL to r3 -> bit-same.
__global__ __launch_bounds__(256)
void spmm_pad(const int* __restrict__ prow, const int* __restrict__ cols,
              const float* __restrict__ vals, const unsigned short* __restrict__ hmat,
              const float* __restrict__ bias, unsigned short* __restrict__ xout) {
    const int wave = threadIdx.x >> 6, lane = threadIdx.x & 63;
    const int r = blockIdx.x * 4 + wave;
    if (r >= NNODES) return;
    const int s = prow[r], e = prow[r + 1];  // length is a multiple of 8
    const int cb = lane * 8;
    floatx2 acc2[4] = {};

    int c[8]; float v[8];
    if (s < e) {
#pragma unroll
        for (int u = 0; u < 8; ++u) { c[u] = cols[s + u]; v[u] = vals[s + u]; }
    }

    for (int i = s; i < e; i += 8) {
        uint4 g[8];
#pragma unroll
        for (int u = 0; u < 8; ++u) g[u] = *(const uint4*)(hmat + (size_t)c[u] * H + cb);

        // prefetch next group's edge data (wave-uniform branch-free clamp)
        const int nx = (i + 8 < e) ? (i + 8) : s;
        int cn[8]; float vn[8];
#pragma unroll
        for (int u = 0; u < 8; ++u) { cn[u] = cols[nx + u]; vn[u] = vals[nx + u]; }

#pragma unroll
        for (int u = 0; u < 8; ++u) {  // real-edge order preserved; pads are exact +0
            const floatx2 vv = {v[u], v[u]};
            union { unsigned int u_; float f; } lo, hi;
            floatx2 p;
            lo.u_ = g[u].x << 16; hi.u_ = g[u].x & 0xffff0000u;
            p[0] = lo.f; p[1] = hi.f; acc2[0] += vv * p;
            lo.u_ = g[u].y << 16; hi.u_ = g[u].y & 0xffff0000u;
            p[0] = lo.f; p[1] = hi.f; acc2[1] += vv * p;
            lo.u_ = g[u].z << 16; hi.u_ = g[u].z & 0xffff0000u;
            p[0] = lo.f; p[1] = hi.f; acc2[2] += vv * p;
            lo.u_ = g[u].w << 16; hi.u_ = g[u].w & 0xffff0000u;
            p[0] = lo.f; p[1] = hi.f; acc2[3] += vv * p;
        }
#pragma unroll
        for (int u = 0; u < 8; ++u) { c[u] = cn[u]; v[u] = vn[u]; }
    }

    short8 o;
#pragma unroll
    for (int k = 0; k < 4; ++k) {
        o[2 * k]     = (short)f2bf(fmaxf(acc2[k][0] + bias[cb + 2 * k], 0.f));
        o[2 * k + 1] = (short)f2bf(fmaxf(acc2[k][1] + bias[cb + 2 * k + 1], 0.f));
    }
    *(short8*)(xout + (size_t)r * H + cb) = o;
}

// ---------- head: out[r] = sigmoid(dot(h2[r,:], w2) + b2) ----------
__global__ __launch_bounds__(256)
void final_head(const unsigned short* __restrict__ h2, const float* __restrict__ w2,
                const float* __restrict__ b2, float* __restrict__ out, int n) {
    const int wave = threadIdx.x >> 6, lane = threadIdx.x & 63;
    const int r = blockIdx.x * 4 + wave;
    if (r >= n) return;
    const unsigned short* hrow = h2 + (size_t)r * H;
    float acc = 0.f;
#pragma unroll
    for (int i = 0; i < 8; ++i) {
        const int c = lane * 8 + i;
        acc += bf2f(hrow[c]) * w2[c];
    }
#pragma unroll
    for (int off = 32; off >= 1; off >>= 1) acc += __shfl_xor(acc, off, 64);
    if (lane == 0) out[r] = 1.f / (1.f + expf(-(acc + b2[0])));
}

extern "C" void kernel_launch(void* const* d_in, const int* in_sizes, int n_in,
                              void* d_out, int out_size, void* d_ws, size_t ws_size,
                              hipStream_t stream) {
    (void)in_sizes; (void)n_in; (void)out_size; (void)ws_size;
    const float* feat   = (const float*)d_in[0];
    const int* adj_row  = (const int*)d_in[1];
    const int* adj_col  = (const int*)d_in[2];
    const float* adj_val= (const float*)d_in[3];
    const float* Wg     = (const float*)d_in[4];
    const float* bg     = (const float*)d_in[5];
    const float* vw1    = (const float*)d_in[6];
    const float* vb1    = (const float*)d_in[7];
    const float* vw2    = (const float*)d_in[8];
    const float* vb2    = (const float*)d_in[9];
    float* out = (float*)d_out;

    // workspace layout (bytes)
    char* ws = (char*)d_ws;
    unsigned short* x  = (unsigned short*)(ws + 0);          // 10,240,000
    unsigned short* h  = (unsigned short*)(ws + 10240000);   // 10,240,000
    unsigned short* Wt = (unsigned short*)(ws + 20480000);   // 3,145,728
    int*   prow    = (int*)(ws + 23625728);                  // 160,064
    int*   counts  = (int*)(ws + 23785792);                  // 40,000
    int*   fill    = (int*)(ws + 23825792);                  // 40,000 (contiguous after counts)
    int*   colsP   = (int*)(ws + 23865792);                  // 960,000 (240k padded edges)
    float* valsP   = (float*)(ws + 24825792);                // 960,000 -> ~25.8 MB

    // --- prep ---
    zero_int<<<(20000 + 255) / 256, 256, 0, stream>>>(counts, 20000);          // counts + fill
    zero_int<<<(480000 + 255) / 256, 256, 0, stream>>>(colsP, 480000);         // colsP + valsP (pad slots)
    cvt_f32_bf16<<<(NNODES * H / 4 + 255) / 256, 256, 0, stream>>>(feat, x, NNODES * H / 4);
    transpose_cvt6<<<dim3(16, 16, 6), dim3(32, 8), 0, stream>>>(Wg, vw1, Wt);
    edge_hist<<<(NEDGES + 255) / 256, 256, 0, stream>>>(adj_row, counts, NEDGES);
    scan_rows_pad<<<1, 1024, 0, stream>>>(counts, prow, NNODES);
    edge_scatter<<<(NEDGES + 255) / 256, 256, 0, stream>>>(adj_row, adj_col, adj_val,
                                                           prow, fill, colsP, valsP, NEDGES);

    // --- layers ---
    for (int l = 0; l < NLAYERS; ++l) {
        gemm_bf16_xcd<<<640, 256, 0, stream>>>(x, Wt + (size_t)l * H * H, h, nullptr, 0, NNODES);
        spmm_pad<<<(NNODES + 3) / 4, 256, 0, stream>>>(prow, colsP, valsP, h, bg + (size_t)l * H, x);
    }
    gemm_bf16_xcd<<<640, 256, 0, stream>>>(x, Wt + (size_t)NLAYERS * H * H, h, vb1, 1, NNODES);
    final_head<<<(NNODES + 3) / 4, 256, 0, stream>>>(h, vw2, vb2, out, NNODES);
}